// Round 11
// baseline (165.593 us; speedup 1.0000x reference)
//
#include <hip/hip_runtime.h>
#include <hip/hip_fp16.h>

// EtaGNN: 2x SAGE-conv (mean agg) + factorized MLP link predictor.
// Strategy: project-then-aggregate (linearity of mean), CSR gather (no f32 atomics),
// factorized query head (A[u]+B[v]+t*wt).
// R1-R3: register-light GEMM evolution; Wm1 pre-split.
// R4: lesson - few-counter global atomics are poison (cross-XCD contention).
// R5: fp16 storage for gathered buffers (rows 256B->128B), f32 accumulate.
// R6: CSR build atomic-free (binned sort via per-block LDS histograms).
// R7: GEMM -> fp16 MFMA 16x16x32, f32 acc, no LDS/barriers. Worked.
// R8: fused agg+gemm per layer; parallel CSR scans; 10 launches. Worked.
// R9: 8-lane uint4 gather groups, 8-deep unroll, 128thr blocks. +9%.
// R10: gathers still latency-bound (31 cyc/gather-instr retire; VALU floor ~1us).
//      16-deep gather unroll (16 loads in flight/lane); query unroll 4.

constexpr int NN = 50000;   // nodes
constexpr int NE = 800000;  // edges
constexpr int NQ = 400000;  // queries
constexpr int NBUCKET = (NN + 127) >> 7;       // 391 buckets of 128 nodes
constexpr int EPB = 4096;                      // edges per scatter block
constexpr int NBLK_S = (NE + EPB - 1) / EPB;   // 196 scatter blocks

// ---------------- CSR build (atomic-free binned sort) ----------------
__global__ __launch_bounds__(256) void hist_kernel(const int* __restrict__ dst,
                                                   int* __restrict__ hist) {
    __shared__ int h[NBUCKET];
    int t = threadIdx.x, blk = blockIdx.x;
    for (int k = t; k < NBUCKET; k += 256) h[k] = 0;
    __syncthreads();
    int base = blk * EPB;
#pragma unroll
    for (int i = 0; i < EPB / 256; ++i) {
        int e = base + t + i * 256;
        if (e < NE) atomicAdd(&h[dst[e] >> 7], 1);
    }
    __syncthreads();
    for (int k = t; k < NBUCKET; k += 256) hist[blk * NBUCKET + k] = h[k];
}

__global__ __launch_bounds__(256) void scanA_kernel(const int* __restrict__ hist,
                                                    int* __restrict__ total) {
    int w = threadIdx.x >> 6, lane = threadIdx.x & 63;
    int k = blockIdx.x * 4 + w;
    if (k >= NBUCKET) return;
    int s = 0;
#pragma unroll
    for (int c = 0; c < 4; ++c) {
        int b = c * 64 + lane;
        if (b < NBLK_S) s += hist[(size_t)b * NBUCKET + k];
    }
#pragma unroll
    for (int off = 32; off > 0; off >>= 1) s += __shfl_down(s, off);
    if (lane == 0) total[k] = s;
}

__global__ __launch_bounds__(512) void scanB_prep_kernel(
    const int* __restrict__ total, int* __restrict__ bucket_base,
    const float* __restrict__ Wm1, float* __restrict__ WmA,
    float* __restrict__ WmB, float* __restrict__ wt) {
    if (blockIdx.x == 0) {
        __shared__ int sd[512];
        int k = threadIdx.x;
        int v0 = (k < NBUCKET) ? total[k] : 0;
        sd[k] = v0; __syncthreads();
        for (int off = 1; off < 512; off <<= 1) {
            int v = sd[k];
            if (k >= off) v += sd[k - off];
            __syncthreads(); sd[k] = v; __syncthreads();
        }
        if (k <= NBUCKET) bucket_base[k] = sd[k] - v0;  // exclusive
    } else {
        int t = threadIdx.x;
        for (int idx = t; idx < 64 * 64; idx += 512) {
            int c = idx >> 6, k = idx & 63;
            WmA[idx] = Wm1[c * 129 + k];
            WmB[idx] = Wm1[c * 129 + 64 + k];
        }
        if (t < 64) wt[t] = Wm1[t * 129 + 128];
    }
}

__global__ __launch_bounds__(256) void scanC_kernel(int* __restrict__ hist,
                                                    const int* __restrict__ bucket_base) {
    int w = threadIdx.x >> 6, lane = threadIdx.x & 63;
    int k = blockIdx.x * 4 + w;
    if (k >= NBUCKET) return;
    int run = bucket_base[k];
#pragma unroll
    for (int c = 0; c < 4; ++c) {
        int b = c * 64 + lane;
        int v = (b < NBLK_S) ? hist[(size_t)b * NBUCKET + k] : 0;
        int orig = v;
#pragma unroll
        for (int off = 1; off < 64; off <<= 1) {
            int u = __shfl_up(v, off);
            if (lane >= off) v += u;
        }
        if (b < NBLK_S) hist[(size_t)b * NBUCKET + k] = run + v - orig;
        run += __shfl(v, 63);
    }
}

__global__ __launch_bounds__(256) void scatter_kernel(const int* __restrict__ src,
                                                      const int* __restrict__ dst,
                                                      const int* __restrict__ hist,
                                                      unsigned* __restrict__ tmp) {
    __shared__ int cur[NBUCKET];
    int t = threadIdx.x, blk = blockIdx.x;
    for (int k = t; k < NBUCKET; k += 256) cur[k] = hist[blk * NBUCKET + k];
    __syncthreads();
    int base = blk * EPB;
#pragma unroll
    for (int i = 0; i < EPB / 256; ++i) {
        int e = base + t + i * 256;
        if (e < NE) {
            int d = dst[e];
            int p = atomicAdd(&cur[d >> 7], 1);
            tmp[p] = ((unsigned)(d & 127) << 16) | (unsigned)src[e];
        }
    }
}

__global__ __launch_bounds__(256) void csr_fill_fused(const int* __restrict__ bucket_base,
                                                      const unsigned* __restrict__ tmp,
                                                      int* __restrict__ csr_src,
                                                      int* __restrict__ row_start) {
    __shared__ int c[128];
    __shared__ int cur[128];
    __shared__ int wtot;
    int b = blockIdx.x;
    int node_base = b << 7;
    int t = threadIdx.x, lane = t & 63, wv = t >> 6;
    if (t < 128) c[t] = 0;
    __syncthreads();
    int s = bucket_base[b], e1 = bucket_base[b + 1];
    for (int i = s + t; i < e1; i += 256) atomicAdd(&c[tmp[i] >> 16], 1);
    __syncthreads();
    int own = (t < 128) ? c[t] : 0;
    int v = own;
#pragma unroll
    for (int off = 1; off < 64; off <<= 1) {
        int u = __shfl_up(v, off);
        if (lane >= off) v += u;
    }
    if (t < 128 && lane == 63 && wv == 0) wtot = v;
    __syncthreads();
    if (t < 128) {
        int excl = v - own + ((wv == 1) ? wtot : 0);
        int pos = s + excl;
        cur[t] = pos;
        int node = node_base + t;
        if (node < NN) row_start[node] = pos;
    }
    if (b == NBUCKET - 1 && t == 0) row_start[NN] = e1;
    __syncthreads();
    for (int i = s + t; i < e1; i += 256) {
        unsigned pk = tmp[i];
        int p = atomicAdd(&cur[pk >> 16], 1);
        csr_src[p] = (int)(pk & 0xFFFFu);
    }
}

// ---------------- MFMA helpers ----------------
typedef _Float16 f16x8 __attribute__((ext_vector_type(8)));
typedef float f32x4 __attribute__((ext_vector_type(4)));

template <typename T>
__device__ inline void store_conv(T* p, float v);
template <> __device__ inline void store_conv<float>(float* p, float v) { *p = v; }
template <> __device__ inline void store_conv<__half>(__half* p, float v) { *p = __float2half(v); }

__device__ inline f16x8 cvt8(float4 a, float4 b) {
    f16x8 r;
    r[0] = (_Float16)a.x; r[1] = (_Float16)a.y; r[2] = (_Float16)a.z; r[3] = (_Float16)a.w;
    r[4] = (_Float16)b.x; r[5] = (_Float16)b.y; r[6] = (_Float16)b.z; r[7] = (_Float16)b.w;
    return r;
}

__device__ inline float2 u2f2(unsigned u) {
    __half2 h = *reinterpret_cast<__half2*>(&u);
    return __half22float2(h);
}

// ---------------- dual MFMA GEMM (layer 1, K=128, input = x) ----------------
template <int K, typename TA, typename TB>
__global__ __launch_bounds__(256) void dual_gemm_mfma(
    const float* __restrict__ in,
    const float* __restrict__ Wa, const float* __restrict__ Wb,
    TA* __restrict__ outA, TB* __restrict__ outB) {
    int t = threadIdx.x;
    int lane = t & 63, w = t >> 6;
    int r0 = blockIdx.x * 64 + w * 16;
    int rl = lane & 15, kg = lane >> 4;
    int gr = r0 + rl; if (gr >= NN) gr = NN - 1;  // clamp; stores guarded
    const float* arow = in + (size_t)gr * K + kg * 8;
    const float* warow = Wa + (size_t)rl * K + kg * 8;
    const float* wbrow = Wb + (size_t)rl * K + kg * 8;
    f32x4 accA[4], accB[4];
#pragma unroll
    for (int ct = 0; ct < 4; ++ct) {
        accA[ct] = (f32x4){0.f, 0.f, 0.f, 0.f};
        accB[ct] = (f32x4){0.f, 0.f, 0.f, 0.f};
    }
    for (int ks = 0; ks < K; ks += 32) {
        float4 a0 = *(const float4*)(arow + ks);
        float4 a1 = *(const float4*)(arow + ks + 4);
        f16x8 af = cvt8(a0, a1);
#pragma unroll
        for (int ct = 0; ct < 4; ++ct) {
            const float* wa = warow + (size_t)ct * 16 * K + ks;
            const float* wb = wbrow + (size_t)ct * 16 * K + ks;
            f16x8 bfA = cvt8(*(const float4*)(wa), *(const float4*)(wa + 4));
            f16x8 bfB = cvt8(*(const float4*)(wb), *(const float4*)(wb + 4));
            accA[ct] = __builtin_amdgcn_mfma_f32_16x16x32_f16(af, bfA, accA[ct], 0, 0, 0);
            accB[ct] = __builtin_amdgcn_mfma_f32_16x16x32_f16(af, bfB, accB[ct], 0, 0, 0);
        }
    }
#pragma unroll
    for (int ct = 0; ct < 4; ++ct) {
#pragma unroll
        for (int i = 0; i < 4; ++i) {
            int row = r0 + kg * 4 + i;
            if (row < NN) {
                store_conv<TA>(&outA[(size_t)row * 64 + ct * 16 + rl], accA[ct][i]);
                store_conv<TB>(&outB[(size_t)row * 64 + ct * 16 + rl], accB[ct][i]);
            }
        }
    }
}

// ---------------- fused agg + dual MFMA GEMM (layers 2,3; K=64) ----------------
// 128 threads = 2 waves, 32 nodes/block. Agg: 16 groups of 8 lanes (uint4 = 8
// halves/lane), 16-deep gather unroll (16 loads in flight). GEMM: wave = 16 rows.
template <typename TA, typename TB>
__global__ __launch_bounds__(128) void fused_agg_gemm(
    const __half* __restrict__ p, const float* __restrict__ selfp,
    const float* __restrict__ bias, const int* __restrict__ row_start,
    const int* __restrict__ csr_src,
    const float* __restrict__ Wa, const float* __restrict__ Wb,
    TA* __restrict__ outA, TB* __restrict__ outB) {
    __shared__ float Xs[32][68];  // padded rows (272B, 16B-aligned)
    int t = threadIdx.x;
    int rbase = blockIdx.x * 32;
    {
        int grp = t >> 3, sub = t & 7;   // 16 groups of 8 lanes
        const uint4* p4 = (const uint4*)p;
#pragma unroll
        for (int pass = 0; pass < 2; ++pass) {
            int nl = pass * 16 + grp;
            int node = rbase + nl;
            float acc[8] = {0.f, 0.f, 0.f, 0.f, 0.f, 0.f, 0.f, 0.f};
            float4 rA = make_float4(0.f, 0.f, 0.f, 0.f);
            float4 rB = make_float4(0.f, 0.f, 0.f, 0.f);
            if (node < NN) {
                int s0 = row_start[node], s1 = row_start[node + 1];
                int e = s0;
                for (; e + 16 <= s1; e += 16) {
                    int idx[16];
#pragma unroll
                    for (int j = 0; j < 16; ++j) idx[j] = csr_src[e + j];
                    uint4 g[16];
#pragma unroll
                    for (int j = 0; j < 16; ++j) g[j] = p4[(size_t)idx[j] * 8 + sub];
#pragma unroll
                    for (int j = 0; j < 16; ++j) {
                        float2 f0 = u2f2(g[j].x), f1 = u2f2(g[j].y);
                        float2 f2 = u2f2(g[j].z), f3 = u2f2(g[j].w);
                        acc[0] += f0.x; acc[1] += f0.y; acc[2] += f1.x; acc[3] += f1.y;
                        acc[4] += f2.x; acc[5] += f2.y; acc[6] += f3.x; acc[7] += f3.y;
                    }
                }
                for (; e + 8 <= s1; e += 8) {
                    int idx[8];
#pragma unroll
                    for (int j = 0; j < 8; ++j) idx[j] = csr_src[e + j];
                    uint4 g[8];
#pragma unroll
                    for (int j = 0; j < 8; ++j) g[j] = p4[(size_t)idx[j] * 8 + sub];
#pragma unroll
                    for (int j = 0; j < 8; ++j) {
                        float2 f0 = u2f2(g[j].x), f1 = u2f2(g[j].y);
                        float2 f2 = u2f2(g[j].z), f3 = u2f2(g[j].w);
                        acc[0] += f0.x; acc[1] += f0.y; acc[2] += f1.x; acc[3] += f1.y;
                        acc[4] += f2.x; acc[5] += f2.y; acc[6] += f3.x; acc[7] += f3.y;
                    }
                }
                for (; e + 4 <= s1; e += 4) {
                    int idx[4];
#pragma unroll
                    for (int j = 0; j < 4; ++j) idx[j] = csr_src[e + j];
                    uint4 g[4];
#pragma unroll
                    for (int j = 0; j < 4; ++j) g[j] = p4[(size_t)idx[j] * 8 + sub];
#pragma unroll
                    for (int j = 0; j < 4; ++j) {
                        float2 f0 = u2f2(g[j].x), f1 = u2f2(g[j].y);
                        float2 f2 = u2f2(g[j].z), f3 = u2f2(g[j].w);
                        acc[0] += f0.x; acc[1] += f0.y; acc[2] += f1.x; acc[3] += f1.y;
                        acc[4] += f2.x; acc[5] += f2.y; acc[6] += f3.x; acc[7] += f3.y;
                    }
                }
                for (; e < s1; ++e) {
                    uint4 g = p4[(size_t)csr_src[e] * 8 + sub];
                    float2 f0 = u2f2(g.x), f1 = u2f2(g.y);
                    float2 f2 = u2f2(g.z), f3 = u2f2(g.w);
                    acc[0] += f0.x; acc[1] += f0.y; acc[2] += f1.x; acc[3] += f1.y;
                    acc[4] += f2.x; acc[5] += f2.y; acc[6] += f3.x; acc[7] += f3.y;
                }
                float inv = 1.f / fmaxf((float)(s1 - s0), 1.f);
                const float4* self4 = (const float4*)selfp;
                float4 sA = self4[(size_t)node * 16 + sub * 2];
                float4 sB = self4[(size_t)node * 16 + sub * 2 + 1];
                float4 bA = ((const float4*)bias)[sub * 2];
                float4 bB = ((const float4*)bias)[sub * 2 + 1];
                rA.x = fmaxf(fmaf(acc[0], inv, bA.x + sA.x), 0.f);
                rA.y = fmaxf(fmaf(acc[1], inv, bA.y + sA.y), 0.f);
                rA.z = fmaxf(fmaf(acc[2], inv, bA.z + sA.z), 0.f);
                rA.w = fmaxf(fmaf(acc[3], inv, bA.w + sA.w), 0.f);
                rB.x = fmaxf(fmaf(acc[4], inv, bB.x + sB.x), 0.f);
                rB.y = fmaxf(fmaf(acc[5], inv, bB.y + sB.y), 0.f);
                rB.z = fmaxf(fmaf(acc[6], inv, bB.z + sB.z), 0.f);
                rB.w = fmaxf(fmaf(acc[7], inv, bB.w + sB.w), 0.f);
            }
            *(float4*)&Xs[nl][sub * 8] = rA;
            *(float4*)&Xs[nl][sub * 8 + 4] = rB;
        }
    }
    __syncthreads();
    int lane = t & 63, w = t >> 6;
    int rl = lane & 15, kg = lane >> 4;
    int lrow = w * 16 + rl;
    const float* warow = Wa + (size_t)rl * 64 + kg * 8;
    const float* wbrow = Wb + (size_t)rl * 64 + kg * 8;
    f32x4 accA[4], accB[4];
#pragma unroll
    for (int ct = 0; ct < 4; ++ct) {
        accA[ct] = (f32x4){0.f, 0.f, 0.f, 0.f};
        accB[ct] = (f32x4){0.f, 0.f, 0.f, 0.f};
    }
#pragma unroll
    for (int ks = 0; ks < 64; ks += 32) {
        float4 a0 = *(const float4*)&Xs[lrow][kg * 8 + ks];
        float4 a1 = *(const float4*)&Xs[lrow][kg * 8 + ks + 4];
        f16x8 af = cvt8(a0, a1);
#pragma unroll
        for (int ct = 0; ct < 4; ++ct) {
            const float* wa = warow + (size_t)ct * 16 * 64 + ks;
            const float* wb = wbrow + (size_t)ct * 16 * 64 + ks;
            f16x8 bfA = cvt8(*(const float4*)(wa), *(const float4*)(wa + 4));
            f16x8 bfB = cvt8(*(const float4*)(wb), *(const float4*)(wb + 4));
            accA[ct] = __builtin_amdgcn_mfma_f32_16x16x32_f16(af, bfA, accA[ct], 0, 0, 0);
            accB[ct] = __builtin_amdgcn_mfma_f32_16x16x32_f16(af, bfB, accB[ct], 0, 0, 0);
        }
    }
    int r0 = rbase + w * 16;
#pragma unroll
    for (int ct = 0; ct < 4; ++ct) {
#pragma unroll
        for (int i = 0; i < 4; ++i) {
            int row = r0 + kg * 4 + i;
            if (row < NN) {
                store_conv<TA>(&outA[(size_t)row * 64 + ct * 16 + rl], accA[ct][i]);
                store_conv<TB>(&outB[(size_t)row * 64 + ct * 16 + rl], accB[ct][i]);
            }
        }
    }
}

// ---------------- query head: out = relu(A[u]+B[v]+t*wt+bm1) . Wm2 + bm2 ----------------
// 8 lanes per query (uint4 = 8 halves/lane); grid-stride, constants hoisted, unroll 4.
__global__ __launch_bounds__(256) void query_kernel(
    const int* __restrict__ uv, const float* __restrict__ tf,
    const __half* __restrict__ A, const __half* __restrict__ B,
    const float* __restrict__ wt, const float* __restrict__ bm1,
    const float* __restrict__ Wm2, const float* __restrict__ bm2,
    float* __restrict__ out) {
    int sub = threadIdx.x & 7;
    int gidx = (blockIdx.x * 256 + threadIdx.x) >> 3;
    int ngroups = (gridDim.x * 256) >> 3;
    const uint4* A4 = (const uint4*)A;
    const uint4* B4 = (const uint4*)B;
    const int2* uv2 = (const int2*)uv;
    float4 wtA = ((const float4*)wt)[sub * 2],  wtB = ((const float4*)wt)[sub * 2 + 1];
    float4 bmA = ((const float4*)bm1)[sub * 2], bmB = ((const float4*)bm1)[sub * 2 + 1];
    float4 wmA = ((const float4*)Wm2)[sub * 2], wmB = ((const float4*)Wm2)[sub * 2 + 1];
    float bm2s = bm2[0];
#pragma unroll 4
    for (int q = gidx; q < NQ; q += ngroups) {
        int2 uvq = uv2[q];
        float t = tf[q];
        uint4 au = A4[(size_t)uvq.x * 8 + sub];
        uint4 bv = B4[(size_t)uvq.y * 8 + sub];
        float2 a0 = u2f2(au.x), a1 = u2f2(au.y), a2 = u2f2(au.z), a3 = u2f2(au.w);
        float2 b0 = u2f2(bv.x), b1 = u2f2(bv.y), b2 = u2f2(bv.z), b3 = u2f2(bv.w);
        float s =
            fmaxf(a0.x + b0.x + t * wtA.x + bmA.x, 0.f) * wmA.x +
            fmaxf(a0.y + b0.y + t * wtA.y + bmA.y, 0.f) * wmA.y +
            fmaxf(a1.x + b1.x + t * wtA.z + bmA.z, 0.f) * wmA.z +
            fmaxf(a1.y + b1.y + t * wtA.w + bmA.w, 0.f) * wmA.w +
            fmaxf(a2.x + b2.x + t * wtB.x + bmB.x, 0.f) * wmB.x +
            fmaxf(a2.y + b2.y + t * wtB.y + bmB.y, 0.f) * wmB.y +
            fmaxf(a3.x + b3.x + t * wtB.z + bmB.z, 0.f) * wmB.z +
            fmaxf(a3.y + b3.y + t * wtB.w + bmB.w, 0.f) * wmB.w;
        s += __shfl_down(s, 4, 8);
        s += __shfl_down(s, 2, 8);
        s += __shfl_down(s, 1, 8);
        if (sub == 0) out[q] = s + bm2s;
    }
}

extern "C" void kernel_launch(void* const* d_in, const int* in_sizes, int n_in,
                              void* d_out, int out_size, void* d_ws, size_t ws_size,
                              hipStream_t stream) {
    const float* x   = (const float*)d_in[0];
    const int*   ei  = (const int*)d_in[1];
    const int*   uv  = (const int*)d_in[2];
    const float* tf  = (const float*)d_in[3];
    const float* W1l = (const float*)d_in[4];
    const float* b1  = (const float*)d_in[5];
    const float* W1r = (const float*)d_in[6];
    const float* W2l = (const float*)d_in[7];
    const float* b2  = (const float*)d_in[8];
    const float* W2r = (const float*)d_in[9];
    const float* Wm1 = (const float*)d_in[10];
    const float* bm1 = (const float*)d_in[11];
    const float* Wm2 = (const float*)d_in[12];
    const float* bm2 = (const float*)d_in[13];
    float* out = (float*)d_out;

    char* ws = (char*)d_ws;
    size_t off = 0;
    auto take = [&](size_t bytes) -> void* {
        void* p = ws + off;
        off = (off + bytes + 255) & ~(size_t)255;
        return p;
    };
    int* row_start = (int*)take((NN + 1) * sizeof(int));
    int* csr_src   = (int*)take((size_t)NE * sizeof(int));
    unsigned* tmp  = (unsigned*)take((size_t)NE * sizeof(unsigned));
    int* hist      = (int*)take((size_t)NBLK_S * NBUCKET * sizeof(int));
    int* total     = (int*)take((NBUCKET + 1) * sizeof(int));
    int* bucket_base = (int*)take((NBUCKET + 1) * sizeof(int));
    float* WmA = (float*)take(64 * 64 * sizeof(float));
    float* WmB = (float*)take(64 * 64 * sizeof(float));
    float* wt  = (float*)take(64 * sizeof(float));
    __half* bufA = (__half*)take((size_t)NN * 64 * sizeof(__half));  // p1 / A
    __half* bufC = (__half*)take((size_t)NN * 64 * sizeof(__half));  // p2
    __half* bufE = (__half*)take((size_t)NN * 64 * sizeof(__half));  // B
    float* bufB = (float*)take((size_t)NN * 64 * sizeof(float));     // s1
    float* bufD = (float*)take((size_t)NN * 64 * sizeof(float));     // s2
    (void)in_sizes; (void)n_in; (void)out_size; (void)ws_size;

    const int* esrc = ei;
    const int* edst = ei + NE;

    // CSR build: hist -> totals -> scan(+Wm1 prep) -> offsets -> scatter -> fused fill
    hist_kernel<<<NBLK_S, 256, 0, stream>>>(edst, hist);
    scanA_kernel<<<(NBUCKET + 3) / 4, 256, 0, stream>>>(hist, total);
    scanB_prep_kernel<<<2, 512, 0, stream>>>(total, bucket_base, Wm1, WmA, WmB, wt);
    scanC_kernel<<<(NBUCKET + 3) / 4, 256, 0, stream>>>(hist, bucket_base);
    scatter_kernel<<<NBLK_S, 256, 0, stream>>>(esrc, edst, hist, tmp);
    csr_fill_fused<<<NBUCKET, 256, 0, stream>>>(bucket_base, tmp, csr_src, row_start);

    // Layer 1: p1 = x@W1l.T (fp16 bufA), s1 = x@W1r.T (f32 bufB)
    dual_gemm_mfma<128, __half, float><<<(NN + 63) / 64, 256, 0, stream>>>(x, W1l, W1r, bufA, bufB);
    // Layer 2 fused: h1 = relu(mean(p1)+b1+s1); p2 = h1@W2l.T (bufC), s2 = h1@W2r.T (bufD)
    fused_agg_gemm<__half, float><<<(NN + 31) / 32, 128, 0, stream>>>(
        bufA, bufB, b1, row_start, csr_src, W2l, W2r, bufC, bufD);
    // Layer 3 fused: h2 = relu(mean(p2)+b2+s2); A = h2@WmA.T (bufA), B = h2@WmB.T (bufE)
    fused_agg_gemm<__half, __half><<<(NN + 31) / 32, 128, 0, stream>>>(
        bufC, bufD, b2, row_start, csr_src, WmA, WmB, bufA, bufE);
    // Per-query head
    query_kernel<<<2048, 256, 0, stream>>>(uv, tf, bufA, bufE, wt, bm1, Wm2, bm2, out);
}

// Round 12
// 149.627 us; speedup vs baseline: 1.1067x; 1.1067x over previous
//
#include <hip/hip_runtime.h>
#include <hip/hip_fp16.h>

// EtaGNN: 2x SAGE-conv (mean agg) + factorized MLP link predictor.
// Strategy: project-then-aggregate (linearity of mean), CSR gather (no f32 atomics),
// factorized query head (A[u]+B[v]+t*wt).
// R1-R3: register-light GEMM evolution; Wm1 pre-split.
// R4: lesson - few-counter global atomics are poison (cross-XCD contention).
// R5: fp16 storage for gathered buffers (rows 256B->128B), f32 accumulate.
// R6: CSR build atomic-free. Lesson: compiler drops prefetch when VGPR-capped.
// R7: GEMM -> fp16 MFMA 16x16x32, f32 acc, no LDS/barriers. Worked.
// R8: fused agg+gemm per layer; parallel CSR scans. Worked.
// R9: 8-lane uint4 gather groups, 8-deep unroll. +9%.
// R10: 16-deep unroll NEUTRAL - VGPR_Count=68 proves allocator sank the loads
//      (default occupancy target). Grid-limited at 12 waves/CU anyway.
// R11: __launch_bounds__(256,3) unlocks 170 VGPR (real 16-deep pipeline) +
//      1 node/group, 32 groups/block, 4 waves/block -> 24 waves/CU.

constexpr int NN = 50000;   // nodes
constexpr int NE = 800000;  // edges
constexpr int NQ = 400000;  // queries
constexpr int NBUCKET = (NN + 127) >> 7;       // 391 buckets of 128 nodes
constexpr int EPB = 4096;                      // edges per scatter block
constexpr int NBLK_S = (NE + EPB - 1) / EPB;   // 196 scatter blocks

// ---------------- CSR build (atomic-free binned sort) ----------------
__global__ __launch_bounds__(256) void hist_kernel(const int* __restrict__ dst,
                                                   int* __restrict__ hist) {
    __shared__ int h[NBUCKET];
    int t = threadIdx.x, blk = blockIdx.x;
    for (int k = t; k < NBUCKET; k += 256) h[k] = 0;
    __syncthreads();
    int base = blk * EPB;
#pragma unroll
    for (int i = 0; i < EPB / 256; ++i) {
        int e = base + t + i * 256;
        if (e < NE) atomicAdd(&h[dst[e] >> 7], 1);
    }
    __syncthreads();
    for (int k = t; k < NBUCKET; k += 256) hist[blk * NBUCKET + k] = h[k];
}

__global__ __launch_bounds__(256) void scanA_kernel(const int* __restrict__ hist,
                                                    int* __restrict__ total) {
    int w = threadIdx.x >> 6, lane = threadIdx.x & 63;
    int k = blockIdx.x * 4 + w;
    if (k >= NBUCKET) return;
    int s = 0;
#pragma unroll
    for (int c = 0; c < 4; ++c) {
        int b = c * 64 + lane;
        if (b < NBLK_S) s += hist[(size_t)b * NBUCKET + k];
    }
#pragma unroll
    for (int off = 32; off > 0; off >>= 1) s += __shfl_down(s, off);
    if (lane == 0) total[k] = s;
}

__global__ __launch_bounds__(512) void scanB_prep_kernel(
    const int* __restrict__ total, int* __restrict__ bucket_base,
    const float* __restrict__ Wm1, float* __restrict__ WmA,
    float* __restrict__ WmB, float* __restrict__ wt) {
    if (blockIdx.x == 0) {
        __shared__ int sd[512];
        int k = threadIdx.x;
        int v0 = (k < NBUCKET) ? total[k] : 0;
        sd[k] = v0; __syncthreads();
        for (int off = 1; off < 512; off <<= 1) {
            int v = sd[k];
            if (k >= off) v += sd[k - off];
            __syncthreads(); sd[k] = v; __syncthreads();
        }
        if (k <= NBUCKET) bucket_base[k] = sd[k] - v0;  // exclusive
    } else {
        int t = threadIdx.x;
        for (int idx = t; idx < 64 * 64; idx += 512) {
            int c = idx >> 6, k = idx & 63;
            WmA[idx] = Wm1[c * 129 + k];
            WmB[idx] = Wm1[c * 129 + 64 + k];
        }
        if (t < 64) wt[t] = Wm1[t * 129 + 128];
    }
}

__global__ __launch_bounds__(256) void scanC_kernel(int* __restrict__ hist,
                                                    const int* __restrict__ bucket_base) {
    int w = threadIdx.x >> 6, lane = threadIdx.x & 63;
    int k = blockIdx.x * 4 + w;
    if (k >= NBUCKET) return;
    int run = bucket_base[k];
#pragma unroll
    for (int c = 0; c < 4; ++c) {
        int b = c * 64 + lane;
        int v = (b < NBLK_S) ? hist[(size_t)b * NBUCKET + k] : 0;
        int orig = v;
#pragma unroll
        for (int off = 1; off < 64; off <<= 1) {
            int u = __shfl_up(v, off);
            if (lane >= off) v += u;
        }
        if (b < NBLK_S) hist[(size_t)b * NBUCKET + k] = run + v - orig;
        run += __shfl(v, 63);
    }
}

__global__ __launch_bounds__(256) void scatter_kernel(const int* __restrict__ src,
                                                      const int* __restrict__ dst,
                                                      const int* __restrict__ hist,
                                                      unsigned* __restrict__ tmp) {
    __shared__ int cur[NBUCKET];
    int t = threadIdx.x, blk = blockIdx.x;
    for (int k = t; k < NBUCKET; k += 256) cur[k] = hist[blk * NBUCKET + k];
    __syncthreads();
    int base = blk * EPB;
#pragma unroll
    for (int i = 0; i < EPB / 256; ++i) {
        int e = base + t + i * 256;
        if (e < NE) {
            int d = dst[e];
            int p = atomicAdd(&cur[d >> 7], 1);
            tmp[p] = ((unsigned)(d & 127) << 16) | (unsigned)src[e];
        }
    }
}

__global__ __launch_bounds__(256) void csr_fill_fused(const int* __restrict__ bucket_base,
                                                      const unsigned* __restrict__ tmp,
                                                      int* __restrict__ csr_src,
                                                      int* __restrict__ row_start) {
    __shared__ int c[128];
    __shared__ int cur[128];
    __shared__ int wtot;
    int b = blockIdx.x;
    int node_base = b << 7;
    int t = threadIdx.x, lane = t & 63, wv = t >> 6;
    if (t < 128) c[t] = 0;
    __syncthreads();
    int s = bucket_base[b], e1 = bucket_base[b + 1];
    for (int i = s + t; i < e1; i += 256) atomicAdd(&c[tmp[i] >> 16], 1);
    __syncthreads();
    int own = (t < 128) ? c[t] : 0;
    int v = own;
#pragma unroll
    for (int off = 1; off < 64; off <<= 1) {
        int u = __shfl_up(v, off);
        if (lane >= off) v += u;
    }
    if (t < 128 && lane == 63 && wv == 0) wtot = v;
    __syncthreads();
    if (t < 128) {
        int excl = v - own + ((wv == 1) ? wtot : 0);
        int pos = s + excl;
        cur[t] = pos;
        int node = node_base + t;
        if (node < NN) row_start[node] = pos;
    }
    if (b == NBUCKET - 1 && t == 0) row_start[NN] = e1;
    __syncthreads();
    for (int i = s + t; i < e1; i += 256) {
        unsigned pk = tmp[i];
        int p = atomicAdd(&cur[pk >> 16], 1);
        csr_src[p] = (int)(pk & 0xFFFFu);
    }
}

// ---------------- MFMA helpers ----------------
typedef _Float16 f16x8 __attribute__((ext_vector_type(8)));
typedef float f32x4 __attribute__((ext_vector_type(4)));

template <typename T>
__device__ inline void store_conv(T* p, float v);
template <> __device__ inline void store_conv<float>(float* p, float v) { *p = v; }
template <> __device__ inline void store_conv<__half>(__half* p, float v) { *p = __float2half(v); }

__device__ inline f16x8 cvt8(float4 a, float4 b) {
    f16x8 r;
    r[0] = (_Float16)a.x; r[1] = (_Float16)a.y; r[2] = (_Float16)a.z; r[3] = (_Float16)a.w;
    r[4] = (_Float16)b.x; r[5] = (_Float16)b.y; r[6] = (_Float16)b.z; r[7] = (_Float16)b.w;
    return r;
}

__device__ inline float2 u2f2(unsigned u) {
    __half2 h = *reinterpret_cast<__half2*>(&u);
    return __half22float2(h);
}

// ---------------- dual MFMA GEMM (layer 1, K=128, input = x) ----------------
template <int K, typename TA, typename TB>
__global__ __launch_bounds__(256) void dual_gemm_mfma(
    const float* __restrict__ in,
    const float* __restrict__ Wa, const float* __restrict__ Wb,
    TA* __restrict__ outA, TB* __restrict__ outB) {
    int t = threadIdx.x;
    int lane = t & 63, w = t >> 6;
    int r0 = blockIdx.x * 64 + w * 16;
    int rl = lane & 15, kg = lane >> 4;
    int gr = r0 + rl; if (gr >= NN) gr = NN - 1;  // clamp; stores guarded
    const float* arow = in + (size_t)gr * K + kg * 8;
    const float* warow = Wa + (size_t)rl * K + kg * 8;
    const float* wbrow = Wb + (size_t)rl * K + kg * 8;
    f32x4 accA[4], accB[4];
#pragma unroll
    for (int ct = 0; ct < 4; ++ct) {
        accA[ct] = (f32x4){0.f, 0.f, 0.f, 0.f};
        accB[ct] = (f32x4){0.f, 0.f, 0.f, 0.f};
    }
    for (int ks = 0; ks < K; ks += 32) {
        float4 a0 = *(const float4*)(arow + ks);
        float4 a1 = *(const float4*)(arow + ks + 4);
        f16x8 af = cvt8(a0, a1);
#pragma unroll
        for (int ct = 0; ct < 4; ++ct) {
            const float* wa = warow + (size_t)ct * 16 * K + ks;
            const float* wb = wbrow + (size_t)ct * 16 * K + ks;
            f16x8 bfA = cvt8(*(const float4*)(wa), *(const float4*)(wa + 4));
            f16x8 bfB = cvt8(*(const float4*)(wb), *(const float4*)(wb + 4));
            accA[ct] = __builtin_amdgcn_mfma_f32_16x16x32_f16(af, bfA, accA[ct], 0, 0, 0);
            accB[ct] = __builtin_amdgcn_mfma_f32_16x16x32_f16(af, bfB, accB[ct], 0, 0, 0);
        }
    }
#pragma unroll
    for (int ct = 0; ct < 4; ++ct) {
#pragma unroll
        for (int i = 0; i < 4; ++i) {
            int row = r0 + kg * 4 + i;
            if (row < NN) {
                store_conv<TA>(&outA[(size_t)row * 64 + ct * 16 + rl], accA[ct][i]);
                store_conv<TB>(&outB[(size_t)row * 64 + ct * 16 + rl], accB[ct][i]);
            }
        }
    }
}

// ---------------- fused agg + dual MFMA GEMM (layers 2,3; K=64) ----------------
// 256 threads = 4 waves, 32 nodes/block, ONE node per 8-lane group (32 concurrent
// gather groups). launch_bounds(256,3) -> VGPR cap 170 so the 16-deep gather
// pipeline stays in registers. MFMA phase: waves 0-1 handle the 2 row-tiles.
template <typename TA, typename TB>
__global__ __launch_bounds__(256, 3) void fused_agg_gemm(
    const __half* __restrict__ p, const float* __restrict__ selfp,
    const float* __restrict__ bias, const int* __restrict__ row_start,
    const int* __restrict__ csr_src,
    const float* __restrict__ Wa, const float* __restrict__ Wb,
    TA* __restrict__ outA, TB* __restrict__ outB) {
    __shared__ float Xs[32][68];  // padded rows (272B, 16B-aligned)
    int t = threadIdx.x;
    int rbase = blockIdx.x * 32;
    {
        int grp = t >> 3, sub = t & 7;   // 32 groups of 8 lanes, 1 node each
        const uint4* p4 = (const uint4*)p;
        int node = rbase + grp;
        float acc[8] = {0.f, 0.f, 0.f, 0.f, 0.f, 0.f, 0.f, 0.f};
        float4 rA = make_float4(0.f, 0.f, 0.f, 0.f);
        float4 rB = make_float4(0.f, 0.f, 0.f, 0.f);
        if (node < NN) {
            int s0 = row_start[node], s1 = row_start[node + 1];
            int e = s0;
            for (; e + 16 <= s1; e += 16) {
                int idx[16];
#pragma unroll
                for (int j = 0; j < 16; ++j) idx[j] = csr_src[e + j];
                uint4 g[16];
#pragma unroll
                for (int j = 0; j < 16; ++j) g[j] = p4[(size_t)idx[j] * 8 + sub];
#pragma unroll
                for (int j = 0; j < 16; ++j) {
                    float2 f0 = u2f2(g[j].x), f1 = u2f2(g[j].y);
                    float2 f2 = u2f2(g[j].z), f3 = u2f2(g[j].w);
                    acc[0] += f0.x; acc[1] += f0.y; acc[2] += f1.x; acc[3] += f1.y;
                    acc[4] += f2.x; acc[5] += f2.y; acc[6] += f3.x; acc[7] += f3.y;
                }
            }
            for (; e + 8 <= s1; e += 8) {
                int idx[8];
#pragma unroll
                for (int j = 0; j < 8; ++j) idx[j] = csr_src[e + j];
                uint4 g[8];
#pragma unroll
                for (int j = 0; j < 8; ++j) g[j] = p4[(size_t)idx[j] * 8 + sub];
#pragma unroll
                for (int j = 0; j < 8; ++j) {
                    float2 f0 = u2f2(g[j].x), f1 = u2f2(g[j].y);
                    float2 f2 = u2f2(g[j].z), f3 = u2f2(g[j].w);
                    acc[0] += f0.x; acc[1] += f0.y; acc[2] += f1.x; acc[3] += f1.y;
                    acc[4] += f2.x; acc[5] += f2.y; acc[6] += f3.x; acc[7] += f3.y;
                }
            }
            for (; e + 4 <= s1; e += 4) {
                int idx[4];
#pragma unroll
                for (int j = 0; j < 4; ++j) idx[j] = csr_src[e + j];
                uint4 g[4];
#pragma unroll
                for (int j = 0; j < 4; ++j) g[j] = p4[(size_t)idx[j] * 8 + sub];
#pragma unroll
                for (int j = 0; j < 4; ++j) {
                    float2 f0 = u2f2(g[j].x), f1 = u2f2(g[j].y);
                    float2 f2 = u2f2(g[j].z), f3 = u2f2(g[j].w);
                    acc[0] += f0.x; acc[1] += f0.y; acc[2] += f1.x; acc[3] += f1.y;
                    acc[4] += f2.x; acc[5] += f2.y; acc[6] += f3.x; acc[7] += f3.y;
                }
            }
            for (; e < s1; ++e) {
                uint4 g = p4[(size_t)csr_src[e] * 8 + sub];
                float2 f0 = u2f2(g.x), f1 = u2f2(g.y);
                float2 f2 = u2f2(g.z), f3 = u2f2(g.w);
                acc[0] += f0.x; acc[1] += f0.y; acc[2] += f1.x; acc[3] += f1.y;
                acc[4] += f2.x; acc[5] += f2.y; acc[6] += f3.x; acc[7] += f3.y;
            }
            float inv = 1.f / fmaxf((float)(s1 - s0), 1.f);
            const float4* self4 = (const float4*)selfp;
            float4 sA = self4[(size_t)node * 16 + sub * 2];
            float4 sB = self4[(size_t)node * 16 + sub * 2 + 1];
            float4 bA = ((const float4*)bias)[sub * 2];
            float4 bB = ((const float4*)bias)[sub * 2 + 1];
            rA.x = fmaxf(fmaf(acc[0], inv, bA.x + sA.x), 0.f);
            rA.y = fmaxf(fmaf(acc[1], inv, bA.y + sA.y), 0.f);
            rA.z = fmaxf(fmaf(acc[2], inv, bA.z + sA.z), 0.f);
            rA.w = fmaxf(fmaf(acc[3], inv, bA.w + sA.w), 0.f);
            rB.x = fmaxf(fmaf(acc[4], inv, bB.x + sB.x), 0.f);
            rB.y = fmaxf(fmaf(acc[5], inv, bB.y + sB.y), 0.f);
            rB.z = fmaxf(fmaf(acc[6], inv, bB.z + sB.z), 0.f);
            rB.w = fmaxf(fmaf(acc[7], inv, bB.w + sB.w), 0.f);
        }
        *(float4*)&Xs[grp][sub * 8] = rA;
        *(float4*)&Xs[grp][sub * 8 + 4] = rB;
    }
    __syncthreads();
    int lane = t & 63, w = t >> 6;
    if (w < 2) {
        int rl = lane & 15, kg = lane >> 4;
        int lrow = w * 16 + rl;
        const float* warow = Wa + (size_t)rl * 64 + kg * 8;
        const float* wbrow = Wb + (size_t)rl * 64 + kg * 8;
        f32x4 accA[4], accB[4];
#pragma unroll
        for (int ct = 0; ct < 4; ++ct) {
            accA[ct] = (f32x4){0.f, 0.f, 0.f, 0.f};
            accB[ct] = (f32x4){0.f, 0.f, 0.f, 0.f};
        }
#pragma unroll
        for (int ks = 0; ks < 64; ks += 32) {
            float4 a0 = *(const float4*)&Xs[lrow][kg * 8 + ks];
            float4 a1 = *(const float4*)&Xs[lrow][kg * 8 + ks + 4];
            f16x8 af = cvt8(a0, a1);
#pragma unroll
            for (int ct = 0; ct < 4; ++ct) {
                const float* wa = warow + (size_t)ct * 16 * 64 + ks;
                const float* wb = wbrow + (size_t)ct * 16 * 64 + ks;
                f16x8 bfA = cvt8(*(const float4*)(wa), *(const float4*)(wa + 4));
                f16x8 bfB = cvt8(*(const float4*)(wb), *(const float4*)(wb + 4));
                accA[ct] = __builtin_amdgcn_mfma_f32_16x16x32_f16(af, bfA, accA[ct], 0, 0, 0);
                accB[ct] = __builtin_amdgcn_mfma_f32_16x16x32_f16(af, bfB, accB[ct], 0, 0, 0);
            }
        }
        int r0 = rbase + w * 16;
#pragma unroll
        for (int ct = 0; ct < 4; ++ct) {
#pragma unroll
            for (int i = 0; i < 4; ++i) {
                int row = r0 + kg * 4 + i;
                if (row < NN) {
                    store_conv<TA>(&outA[(size_t)row * 64 + ct * 16 + rl], accA[ct][i]);
                    store_conv<TB>(&outB[(size_t)row * 64 + ct * 16 + rl], accB[ct][i]);
                }
            }
        }
    }
}

// ---------------- query head: out = relu(A[u]+B[v]+t*wt+bm1) . Wm2 + bm2 ----------------
// 8 lanes per query (uint4 = 8 halves/lane); grid-stride, constants hoisted, unroll 4.
__global__ __launch_bounds__(256) void query_kernel(
    const int* __restrict__ uv, const float* __restrict__ tf,
    const __half* __restrict__ A, const __half* __restrict__ B,
    const float* __restrict__ wt, const float* __restrict__ bm1,
    const float* __restrict__ Wm2, const float* __restrict__ bm2,
    float* __restrict__ out) {
    int sub = threadIdx.x & 7;
    int gidx = (blockIdx.x * 256 + threadIdx.x) >> 3;
    int ngroups = (gridDim.x * 256) >> 3;
    const uint4* A4 = (const uint4*)A;
    const uint4* B4 = (const uint4*)B;
    const int2* uv2 = (const int2*)uv;
    float4 wtA = ((const float4*)wt)[sub * 2],  wtB = ((const float4*)wt)[sub * 2 + 1];
    float4 bmA = ((const float4*)bm1)[sub * 2], bmB = ((const float4*)bm1)[sub * 2 + 1];
    float4 wmA = ((const float4*)Wm2)[sub * 2], wmB = ((const float4*)Wm2)[sub * 2 + 1];
    float bm2s = bm2[0];
#pragma unroll 4
    for (int q = gidx; q < NQ; q += ngroups) {
        int2 uvq = uv2[q];
        float t = tf[q];
        uint4 au = A4[(size_t)uvq.x * 8 + sub];
        uint4 bv = B4[(size_t)uvq.y * 8 + sub];
        float2 a0 = u2f2(au.x), a1 = u2f2(au.y), a2 = u2f2(au.z), a3 = u2f2(au.w);
        float2 b0 = u2f2(bv.x), b1 = u2f2(bv.y), b2 = u2f2(bv.z), b3 = u2f2(bv.w);
        float s =
            fmaxf(a0.x + b0.x + t * wtA.x + bmA.x, 0.f) * wmA.x +
            fmaxf(a0.y + b0.y + t * wtA.y + bmA.y, 0.f) * wmA.y +
            fmaxf(a1.x + b1.x + t * wtA.z + bmA.z, 0.f) * wmA.z +
            fmaxf(a1.y + b1.y + t * wtA.w + bmA.w, 0.f) * wmA.w +
            fmaxf(a2.x + b2.x + t * wtB.x + bmB.x, 0.f) * wmB.x +
            fmaxf(a2.y + b2.y + t * wtB.y + bmB.y, 0.f) * wmB.y +
            fmaxf(a3.x + b3.x + t * wtB.z + bmB.z, 0.f) * wmB.z +
            fmaxf(a3.y + b3.y + t * wtB.w + bmB.w, 0.f) * wmB.w;
        s += __shfl_down(s, 4, 8);
        s += __shfl_down(s, 2, 8);
        s += __shfl_down(s, 1, 8);
        if (sub == 0) out[q] = s + bm2s;
    }
}

extern "C" void kernel_launch(void* const* d_in, const int* in_sizes, int n_in,
                              void* d_out, int out_size, void* d_ws, size_t ws_size,
                              hipStream_t stream) {
    const float* x   = (const float*)d_in[0];
    const int*   ei  = (const int*)d_in[1];
    const int*   uv  = (const int*)d_in[2];
    const float* tf  = (const float*)d_in[3];
    const float* W1l = (const float*)d_in[4];
    const float* b1  = (const float*)d_in[5];
    const float* W1r = (const float*)d_in[6];
    const float* W2l = (const float*)d_in[7];
    const float* b2  = (const float*)d_in[8];
    const float* W2r = (const float*)d_in[9];
    const float* Wm1 = (const float*)d_in[10];
    const float* bm1 = (const float*)d_in[11];
    const float* Wm2 = (const float*)d_in[12];
    const float* bm2 = (const float*)d_in[13];
    float* out = (float*)d_out;

    char* ws = (char*)d_ws;
    size_t off = 0;
    auto take = [&](size_t bytes) -> void* {
        void* p = ws + off;
        off = (off + bytes + 255) & ~(size_t)255;
        return p;
    };
    int* row_start = (int*)take((NN + 1) * sizeof(int));
    int* csr_src   = (int*)take((size_t)NE * sizeof(int));
    unsigned* tmp  = (unsigned*)take((size_t)NE * sizeof(unsigned));
    int* hist      = (int*)take((size_t)NBLK_S * NBUCKET * sizeof(int));
    int* total     = (int*)take((NBUCKET + 1) * sizeof(int));
    int* bucket_base = (int*)take((NBUCKET + 1) * sizeof(int));
    float* WmA = (float*)take(64 * 64 * sizeof(float));
    float* WmB = (float*)take(64 * 64 * sizeof(float));
    float* wt  = (float*)take(64 * sizeof(float));
    __half* bufA = (__half*)take((size_t)NN * 64 * sizeof(__half));  // p1 / A
    __half* bufC = (__half*)take((size_t)NN * 64 * sizeof(__half));  // p2
    __half* bufE = (__half*)take((size_t)NN * 64 * sizeof(__half));  // B
    float* bufB = (float*)take((size_t)NN * 64 * sizeof(float));     // s1
    float* bufD = (float*)take((size_t)NN * 64 * sizeof(float));     // s2
    (void)in_sizes; (void)n_in; (void)out_size; (void)ws_size;

    const int* esrc = ei;
    const int* edst = ei + NE;

    // CSR build: hist -> totals -> scan(+Wm1 prep) -> offsets -> scatter -> fused fill
    hist_kernel<<<NBLK_S, 256, 0, stream>>>(edst, hist);
    scanA_kernel<<<(NBUCKET + 3) / 4, 256, 0, stream>>>(hist, total);
    scanB_prep_kernel<<<2, 512, 0, stream>>>(total, bucket_base, Wm1, WmA, WmB, wt);
    scanC_kernel<<<(NBUCKET + 3) / 4, 256, 0, stream>>>(hist, bucket_base);
    scatter_kernel<<<NBLK_S, 256, 0, stream>>>(esrc, edst, hist, tmp);
    csr_fill_fused<<<NBUCKET, 256, 0, stream>>>(bucket_base, tmp, csr_src, row_start);

    // Layer 1: p1 = x@W1l.T (fp16 bufA), s1 = x@W1r.T (f32 bufB)
    dual_gemm_mfma<128, __half, float><<<(NN + 63) / 64, 256, 0, stream>>>(x, W1l, W1r, bufA, bufB);
    // Layer 2 fused: h1 = relu(mean(p1)+b1+s1); p2 = h1@W2l.T (bufC), s2 = h1@W2r.T (bufD)
    fused_agg_gemm<__half, float><<<(NN + 31) / 32, 256, 0, stream>>>(
        bufA, bufB, b1, row_start, csr_src, W2l, W2r, bufC, bufD);
    // Layer 3 fused: h2 = relu(mean(p2)+b2+s2); A = h2@WmA.T (bufA), B = h2@WmB.T (bufE)
    fused_agg_gemm<__half, __half><<<(NN + 31) / 32, 256, 0, stream>>>(
        bufC, bufD, b2, row_start, csr_src, WmA, WmB, bufA, bufE);
    // Per-query head
    query_kernel<<<2048, 256, 0, stream>>>(uv, tf, bufA, bufE, wt, bm1, Wm2, bm2, out);
}